// Round 13
// baseline (47.251 us; speedup 1.0000x reference)
//
#include <hip/hip_runtime.h>

#define PS    25
#define PADW  12
#define EPSV  (1.0f/255.0f)
#define WW    512
#define HH    512
#define NB    16

#define TW    64                 // output tile width
#define TH    32                 // output tile height
#define NTILE 4                  // y-tiles per block (persistent)
#define IWn   (TW + 2*PADW)      // 88 halo cols
#define IHn   (TH + 2*PADW)      // 56 halo rows
#define IWS   88                 // LDS stride
#define NPX4  (IHn * (IWn/4))    // 1232 float4 groups
#define NCG   (IWn/4)            // 22 column groups
#define NCP   (IWn/2)            // 44 column pairs (stage 2)
#define NT2   (2 * 2 * NCP)      // 176 stage-2 tasks

#define INV625 (1.0f/625.0f)

__device__ __forceinline__ int reflectI(int i, int n) {
    if (i < 0)  i = -i;
    if (i >= n) i = 2 * n - 2 - i;
    return i;
}

__device__ __forceinline__ float fastrcp(float x) {
    float y;
    asm("v_rcp_f32 %0, %1" : "=v"(y) : "v"(x));
    return y;
}

// Load 4 consecutive halo cols [gx0..gx0+3] of (already-reflected) row gy.
// In-bounds: direct float4. Out-of-bounds (x-edge tiles only): reflection of
// a contiguous descending range == reversed float4 at the mirrored base.
__device__ __forceinline__ float4 load_group(const float* __restrict__ p,
                                             int gy, int gx0)
{
    const float* row = p + (size_t)gy * WW;
    if (gx0 >= 0 && gx0 <= WW - 4) {
        return *(const float4*)(row + gx0);
    } else if (gx0 < 0) {
        float4 v = *(const float4*)(row + (-gx0 - 3));       // cols -gx0-3 .. -gx0
        return make_float4(v.w, v.z, v.y, v.x);              // reversed
    } else {
        float4 v = *(const float4*)(row + (2*WW - 5 - gx0)); // 1019-gx0
        return make_float4(v.w, v.z, v.y, v.x);
    }
}

__device__ __forceinline__ void ms_from_rgb(const float4& r4, const float4& g4,
                                            const float4& b4,
                                            float4& m4, float4& s4)
{
    float r[4] = {r4.x, r4.y, r4.z, r4.w};
    float g[4] = {g4.x, g4.y, g4.z, g4.w};
    float b[4] = {b4.x, b4.y, b4.z, b4.w};
    float m[4], s[4];
#pragma unroll
    for (int j = 0; j < 4; ++j) {
        m[j] = (r[j] + g[j] + b[j]) * (1.0f/3.0f);
        s[j] = fmaf(r[j], r[j], fmaf(g[j], g[j], b[j]*b[j])) * (1.0f/3.0f);
    }
    m4 = make_float4(m[0], m[1], m[2], m[3]);
    s4 = make_float4(s[0], s[1], s[2], s[3]);
}

__global__ __launch_bounds__(512, 4)
void fused_tile(const float* __restrict__ img, float* __restrict__ out)
{
    const int t   = threadIdx.x;
    const int x0  = blockIdx.x * TW;
    const int gyb = blockIdx.y;           // 0..3  -> y-tiles 4*gyb..4*gyb+3
    const int b   = blockIdx.z;

    __shared__ float smM[2][IHn][IWS];    // double-buffered channel-mean
    __shared__ float smS[2][IHn][IWS];    // double-buffered mean-of-squares

    const size_t plane = (size_t)WW * HH;
    const float* pR = img + (size_t)b * 3 * plane;
    const float* pG = pR + plane;
    const float* pB = pR + 2 * plane;

    // ---- prologue: load tile 0 into buffer 0 ----
    {
        const int y0 = (gyb * NTILE) * TH;
        for (int i = t; i < NPX4; i += 512) {
            int iy = i / NCG;
            int ix = i - iy * NCG;
            int gy  = reflectI(y0 - PADW + iy, HH);
            int gx0 = x0 - PADW + 4 * ix;
            float4 r4 = load_group(pR, gy, gx0);
            float4 g4 = load_group(pG, gy, gx0);
            float4 b4 = load_group(pB, gy, gx0);
            float4 m4, s4;
            ms_from_rgb(r4, g4, b4, m4, s4);
            *(float4*)&smM[0][iy][ix * 4] = m4;
            *(float4*)&smS[0][iy][ix * 4] = s4;
        }
    }
    __syncthreads();

    int cur = 0;
    for (int tile = 0; tile < NTILE; ++tile) {
        const int y0 = (gyb * NTILE + tile) * TH;

        // ---- step 1: issue next-tile prefetch + this tile's sat loads ----
        float4 nr[3], ng[3], nb[3];
        const bool havePf = (tile + 1 < NTILE);
        if (havePf) {
            const int ny0 = y0 + TH;
#pragma unroll
            for (int k = 0; k < 3; ++k) {
                const int i = t + k * 512;
                if (i < NPX4) {
                    int iy = i / NCG;
                    int ix = i - iy * NCG;
                    int gy  = reflectI(ny0 - PADW + iy, HH);
                    int gx0 = x0 - PADW + 4 * ix;
                    nr[k] = load_group(pR, gy, gx0);
                    ng[k] = load_group(pG, gy, gx0);
                    nb[k] = load_group(pB, gy, gx0);
                }
            }
        }
        const int r  = t >> 4;          // 0..31 output row
        const int c4 = (t & 15) * 4;    // 0..60 output col group
        const size_t ro = (size_t)(y0 + r) * WW + x0 + c4;
        const float4 ra = *(const float4*)(pR + ro);
        const float4 ga = *(const float4*)(pG + ro);
        const float4 ba = *(const float4*)(pB + ro);

        float (*bM)[IWS] = smM[cur];
        float (*bS)[IWS] = smS[cur];

        // ---- step 2: vertical 25-tap float2 forward scans (176 tasks) ----
        // seg0: outputs 0..15 -> rows 0..15 in place.
        // seg1: outputs 16..31 -> parked in dead halo rows 40..55.
        if (t < NT2) {
            int rem = t;
            float (*buf)[IWS] = bM;
            if (rem >= 2 * NCP) { buf = bS; rem -= 2 * NCP; }
            const bool seg1 = (rem >= NCP);
            const int  xp   = (seg1 ? rem - NCP : rem) * 2;

            if (!seg1) {
                float2 old = *(const float2*)&buf[0][xp];
                float2 run = old;
#pragma unroll
                for (int k = 1; k < PS; ++k) {
                    float2 v = *(const float2*)&buf[k][xp];
                    run.x += v.x; run.y += v.y;
                }
                *(float2*)&buf[0][xp] = run;
#pragma unroll
                for (int y = 1; y < 16; ++y) {
                    float2 c2 = *(const float2*)&buf[y][xp];
                    float2 nw = *(const float2*)&buf[y + PS - 1][xp];
                    run.x += nw.x - old.x; run.y += nw.y - old.y;
                    *(float2*)&buf[y][xp] = run;
                    old = c2;
                }
            } else {
                float2 run = make_float2(0.f, 0.f);
#pragma unroll
                for (int k = 16; k < 16 + PS; ++k) {
                    float2 v = *(const float2*)&buf[k][xp];
                    run.x += v.x; run.y += v.y;
                }
                *(float2*)&buf[40][xp] = run;
#pragma unroll
                for (int y = 17; y < 32; ++y) {
                    float2 nw = *(const float2*)&buf[y + PS - 1][xp];
                    float2 og = *(const float2*)&buf[y - 1][xp];
                    run.x += nw.x - og.x; run.y += nw.y - og.y;
                    *(float2*)&buf[y + PS - 1][xp] = run;
                }
            }
        }
        __syncthreads();

        // ---- step 3: horizontal 25-tap + sat + output ----
        const int vr = (r < 16) ? r : r + 24;

        float wm[28], ws[28];
#pragma unroll
        for (int i = 0; i < 7; ++i) {
            float4 a = *(const float4*)&bM[vr][c4 + 4*i];
            float4 c = *(const float4*)&bS[vr][c4 + 4*i];
            wm[4*i]=a.x; wm[4*i+1]=a.y; wm[4*i+2]=a.z; wm[4*i+3]=a.w;
            ws[4*i]=c.x; ws[4*i+1]=c.y; ws[4*i+2]=c.z; ws[4*i+3]=c.w;
        }
        float hm = 0.f, hs = 0.f;
#pragma unroll
        for (int i = 0; i < PS; ++i) { hm += wm[i]; hs += ws[i]; }

        float rr[4] = {ra.x, ra.y, ra.z, ra.w};
        float gg[4] = {ga.x, ga.y, ga.z, ga.w};
        float bb[4] = {ba.x, ba.y, ba.z, ba.w};

        float sc[4];
#pragma unroll
        for (int j = 0; j < 4; ++j) {
            if (j > 0) {
                hm += wm[PS - 1 + j] - wm[j - 1];
                hs += ws[PS - 1 + j] - ws[j - 1];
            }
            float mx = fmaxf(rr[j], fmaxf(gg[j], bb[j]));
            float mn = fminf(rr[j], fminf(gg[j], bb[j]));
            float sat = (mx - mn + EPSV) * fastrcp(mx + EPSV);

            float mean     = hm * INV625;
            float msq      = hs * INV625;
            float contrast = fmaf(-mean, mean, msq);
            float expo     = fabsf(mean - 0.5f) + EPSV;
            sc[j] = sat * contrast * fastrcp(expo);
        }
        float* orow = out + ((size_t)b * HH + (y0 + r)) * WW + x0 + c4;
        *(float4*)orow = make_float4(sc[0], sc[1], sc[2], sc[3]);

        // ---- step 4: write prefetched tile into the other buffer ----
        if (havePf) {
            float (*nM)[IWS] = smM[cur ^ 1];
            float (*nS)[IWS] = smS[cur ^ 1];
#pragma unroll
            for (int k = 0; k < 3; ++k) {
                const int i = t + k * 512;
                if (i < NPX4) {
                    int iy = i / NCG;
                    int ix = i - iy * NCG;
                    float4 m4, s4;
                    ms_from_rgb(nr[k], ng[k], nb[k], m4, s4);
                    *(float4*)&nM[iy][ix * 4] = m4;
                    *(float4*)&nS[iy][ix * 4] = s4;
                }
            }
            __syncthreads();
            cur ^= 1;
        }
    }
}

extern "C" void kernel_launch(void* const* d_in, const int* in_sizes, int n_in,
                              void* d_out, int out_size, void* d_ws, size_t ws_size,
                              hipStream_t stream)
{
    const float* img = (const float*)d_in[0];
    float* out = (float*)d_out;

    dim3 grid(WW / TW, HH / (TH * NTILE), NB);   // 8 x 4 x 16 = 512 blocks
    fused_tile<<<grid, 512, 0, stream>>>(img, out);
}

// Round 14
// 31.733 us; speedup vs baseline: 1.4890x; 1.4890x over previous
//
#include <hip/hip_runtime.h>

#define PS    25
#define PADW  12
#define EPSV  (1.0f/255.0f)
#define WW    512
#define HH    512
#define NB    16

#define TW    64                 // output tile width
#define TH    32                 // output tile height
#define IWn   (TW + 2*PADW)      // 88 halo cols
#define IHn   (TH + 2*PADW)      // 56 halo rows
#define IWS   88                 // LDS stride (mult of 4 -> b128-aligned)
#define NPX   (IWn * IHn)        // 4928 halo pixels (scalar path)
#define NPX4  (IHn * (IWn/4))    // 1232 float4 groups (fast path)
#define NCG   (IWn/4)            // 22 column groups
#define NCP   (IWn/2)            // 44 column pairs (stage 2)
#define NT2   (2 * 2 * NCP)      // 176 stage-2 tasks

#define INV625 (1.0f/625.0f)

__device__ __forceinline__ int reflectI(int i, int n) {
    if (i < 0)  i = -i;
    if (i >= n) i = 2 * n - 2 - i;
    return i;
}

__device__ __forceinline__ float fastrcp(float x) {
    float y;
    asm("v_rcp_f32 %0, %1" : "=v"(y) : "v"(x));
    return y;
}

__global__ __launch_bounds__(512, 8)
void fused_tile(const float* __restrict__ img, float* __restrict__ out)
{
    const int t  = threadIdx.x;
    const int x0 = blockIdx.x * TW;
    const int y0 = blockIdx.y * TH;
    const int b  = blockIdx.z;

    // stage 2 overwrites rows 0..15 (seg0, in place) and rows 40..55 (seg1's
    // sums parked in the dead tail halo) -- hazard-free forward scans.
    __shared__ float smM[IHn][IWS];   // channel-mean            (56x88)
    __shared__ float smS[IHn][IWS];   // channel-mean of squares (56x88)

    const size_t plane = (size_t)WW * HH;
    const float* pR = img + (size_t)b * 3 * plane;
    const float* pG = pR + plane;
    const float* pB = pR + 2 * plane;

    const bool interior = (x0 >= PADW) && (x0 + TW + PADW <= WW) &&
                          (y0 >= PADW) && (y0 + TH + PADW <= HH);

    // ---- stage 1: load halo, compute m,s into LDS ----
    if (interior) {
        const size_t base = (size_t)(y0 - PADW) * WW + (x0 - PADW);
        // incremental iy/ix (group units): avoids /22,%22 per iteration
        int iy = t / NCG;
        int ix = t - iy * NCG;
#pragma unroll 3
        for (int i = t; i < NPX4; i += 512) {
            size_t off = base + (size_t)(iy << 9) + (ix << 2);
            float4 ra = *(const float4*)(pR + off);
            float4 ga = *(const float4*)(pG + off);
            float4 ba = *(const float4*)(pB + off);
            float r[4]  = {ra.x, ra.y, ra.z, ra.w};
            float g[4]  = {ga.x, ga.y, ga.z, ga.w};
            float bl[4] = {ba.x, ba.y, ba.z, ba.w};
            float m[4], s[4];
#pragma unroll
            for (int j = 0; j < 4; ++j) {
                m[j] = (r[j] + g[j] + bl[j]) * (1.0f/3.0f);
                s[j] = fmaf(r[j], r[j], fmaf(g[j], g[j], bl[j]*bl[j])) * (1.0f/3.0f);
            }
            *(float4*)&smM[iy][ix << 2] = make_float4(m[0], m[1], m[2], m[3]);
            *(float4*)&smS[iy][ix << 2] = make_float4(s[0], s[1], s[2], s[3]);
            // advance 512 groups = 23 rows + 6 groups (512 = 23*22 + 6)
            iy += 23; ix += 6;
            if (ix >= NCG) { ix -= NCG; iy += 1; }
        }
    } else {
        for (int i = t; i < NPX; i += 512) {
            int iy = i / IWn;
            int ix = i - iy * IWn;
            int gy = reflectI(y0 - PADW + iy, HH);
            int gx = reflectI(x0 - PADW + ix, WW);
            size_t idx = (size_t)gy * WW + gx;
            float r  = pR[idx];
            float g  = pG[idx];
            float bl = pB[idx];
            smM[iy][ix] = (r + g + bl) * (1.0f/3.0f);
            smS[iy][ix] = fmaf(r, r, fmaf(g, g, bl*bl)) * (1.0f/3.0f);
        }
    }
    __syncthreads();

    // ---- early sat loads (T14): issue now, latency hides under stage 2 ----
    const int r  = t >> 4;          // 0..31 output row
    const int c4 = (t & 15) * 4;    // 0..60 output col group
    const size_t ro = (size_t)(y0 + r) * WW + x0 + c4;
    const float4 ra = *(const float4*)(pR + ro);
    const float4 ga = *(const float4*)(pG + ro);
    const float4 ba = *(const float4*)(pB + ro);

    // ---- stage 2: vertical 25-tap float2 forward scans (176 tasks) ----
    // seg0: outputs 0..15, reads rows 0..39, writes rows 0..15 (in place).
    // seg1: outputs 16..31, reads rows 16..55, writes rows 40..55 (dead halo).
    if (t < NT2) {
        int rem = t;
        float (*buf)[IWS] = smM;
        if (rem >= 2 * NCP) { buf = smS; rem -= 2 * NCP; }
        const bool seg1 = (rem >= NCP);
        const int  xp   = (seg1 ? rem - NCP : rem) * 2;

        if (!seg1) {
            float2 old = *(const float2*)&buf[0][xp];
            float2 run = old;
#pragma unroll
            for (int k = 1; k < PS; ++k) {
                float2 v = *(const float2*)&buf[k][xp];
                run.x += v.x; run.y += v.y;
            }
            *(float2*)&buf[0][xp] = run;
#pragma unroll
            for (int y = 1; y < 16; ++y) {
                float2 cur = *(const float2*)&buf[y][xp];       // original
                float2 nw  = *(const float2*)&buf[y + PS - 1][xp];
                run.x += nw.x - old.x; run.y += nw.y - old.y;
                *(float2*)&buf[y][xp] = run;
                old = cur;
            }
        } else {
            float2 run = make_float2(0.f, 0.f);
#pragma unroll
            for (int k = 16; k < 16 + PS; ++k) {
                float2 v = *(const float2*)&buf[k][xp];
                run.x += v.x; run.y += v.y;
            }
            *(float2*)&buf[40][xp] = run;                       // row16 -> 40
#pragma unroll
            for (int y = 17; y < 32; ++y) {
                float2 nw = *(const float2*)&buf[y + PS - 1][xp]; // original
                float2 og = *(const float2*)&buf[y - 1][xp];      // original
                run.x += nw.x - og.x; run.y += nw.y - og.y;
                *(float2*)&buf[y + PS - 1][xp] = run;             // park y+24
            }
        }
    }
    __syncthreads();

    // ---- stage 3: horizontal 25-tap, streaming window (low reg pressure) ----
    // Only the first (m0/s0) and last (m6/s6) float4 of the 28-col window are
    // kept live; the middle 5 groups fold into a running sum and die.
    const int vr = (r < 16) ? r : r + 24;   // vertical-sum row location
    const float* mrow = &smM[vr][c4];
    const float* srow = &smS[vr][c4];

    const float4 m0 = *(const float4*)(mrow);
    const float4 s0 = *(const float4*)(srow);
    const float4 m6 = *(const float4*)(mrow + 24);
    const float4 s6 = *(const float4*)(srow + 24);

    float midm = 0.f, mids = 0.f;
#pragma unroll
    for (int i = 1; i <= 5; ++i) {
        float4 a = *(const float4*)(mrow + 4 * i);
        float4 c = *(const float4*)(srow + 4 * i);
        midm += (a.x + a.y) + (a.z + a.w);
        mids += (c.x + c.y) + (c.z + c.w);
    }

    float hm = (m0.x + m0.y) + (m0.z + m0.w) + midm + m6.x;
    float hs = (s0.x + s0.y) + (s0.z + s0.w) + mids + s6.x;

    float rr[4] = {ra.x, ra.y, ra.z, ra.w};
    float gg[4] = {ga.x, ga.y, ga.z, ga.w};
    float bb[4] = {ba.x, ba.y, ba.z, ba.w};
    const float oldm[3] = {m0.x, m0.y, m0.z};
    const float olds[3] = {s0.x, s0.y, s0.z};
    const float newm[3] = {m6.y, m6.z, m6.w};
    const float news[3] = {s6.y, s6.z, s6.w};

    float sc[4];
#pragma unroll
    for (int j = 0; j < 4; ++j) {
        if (j > 0) {
            hm += newm[j - 1] - oldm[j - 1];
            hs += news[j - 1] - olds[j - 1];
        }
        float mx = fmaxf(rr[j], fmaxf(gg[j], bb[j]));
        float mn = fminf(rr[j], fminf(gg[j], bb[j]));
        float sat = (mx - mn + EPSV) * fastrcp(mx + EPSV);

        float mean     = hm * INV625;
        float msq      = hs * INV625;
        float contrast = fmaf(-mean, mean, msq);
        float expo     = fabsf(mean - 0.5f) + EPSV;
        sc[j] = sat * contrast * fastrcp(expo);
    }
    float* orow = out + ((size_t)b * HH + (y0 + r)) * WW + x0 + c4;
    *(float4*)orow = make_float4(sc[0], sc[1], sc[2], sc[3]);
}

extern "C" void kernel_launch(void* const* d_in, const int* in_sizes, int n_in,
                              void* d_out, int out_size, void* d_ws, size_t ws_size,
                              hipStream_t stream)
{
    const float* img = (const float*)d_in[0];
    float* out = (float*)d_out;

    dim3 grid(WW / TW, HH / TH, NB);   // 8 x 16 x 16 = 2048 blocks
    fused_tile<<<grid, 512, 0, stream>>>(img, out);
}